// Round 9
// baseline (299.984 us; speedup 1.0000x reference)
//
#include <hip/hip_runtime.h>
#include <hip/hip_bf16.h>

#define BB 4
#define CC 64
#define DD 8
#define NN 32768
#define WW 512
#define STR 256
#define NWIN 127
#define LOG2E 1.4426950408889634f

typedef short bf16x8 __attribute__((ext_vector_type(8)));
typedef float f32x4 __attribute__((ext_vector_type(4)));
typedef float f32x16 __attribute__((ext_vector_type(16)));

__device__ __forceinline__ unsigned int pack_bf16(float lo, float hi) {
    __hip_bfloat162 h = __float22bfloat162_rn(make_float2(lo, hi));  // v_cvt_pk_bf16_f32
    unsigned int r; __builtin_memcpy(&r, &h, 4);
    return r;
}
__device__ __forceinline__ unsigned short to_bf16(float f) {
    __hip_bfloat16 h = __float2bfloat16(f);
    unsigned short r; __builtin_memcpy(&r, &h, 2);
    return r;
}
__device__ __forceinline__ float bf2f(unsigned short s) {
    union { unsigned int u; float f; } v; v.u = ((unsigned int)s) << 16;
    return v.f;
}
// guaranteed single v_exp_f32 (exp2f() is an ocml expansion)
__device__ __forceinline__ float fast_exp2(float x) {
#if __has_builtin(__builtin_amdgcn_exp2f)
    return __builtin_amdgcn_exp2f(x);
#else
    float r; asm("v_exp_f32 %0, %1" : "=v"(r) : "v"(x)); return r;
#endif
}
// swap upper 32 lanes of x with lower 32 lanes of y (gfx950)
__device__ __forceinline__ void plswap(unsigned int &x, unsigned int &y) {
    asm("v_permlane32_swap_b32 %0, %1" : "+v"(x), "+v"(y));
}
__device__ __forceinline__ bf16x8 pack8(float a0, float a1, float a2, float a3,
                                        float a4, float a5, float a6, float a7) {
    union { bf16x8 v; unsigned int u[4]; } r;
    r.u[0] = pack_bf16(a0, a1); r.u[1] = pack_bf16(a2, a3);
    r.u[2] = pack_bf16(a4, a5); r.u[3] = pack_bf16(a6, a7);
    return r.v;
}
__device__ __forceinline__ bf16x8 words4(unsigned int w0, unsigned int w1,
                                         unsigned int w2, unsigned int w3) {
    union { bf16x8 v; unsigned int u[4]; } r;
    r.u[0] = w0; r.u[1] = w1; r.u[2] = w2; r.u[3] = w3;
    return r.v;
}

// ---------------- kernel 1: QKV projection as MFMA GEMM ----------------
__global__ __launch_bounds__(256) void qkv_kernel(
    const float* __restrict__ x,
    const float* __restrict__ Wq, const float* __restrict__ bq,
    const float* __restrict__ Wk, const float* __restrict__ bk,
    const float* __restrict__ Wv, const float* __restrict__ bv,
    unsigned short* __restrict__ qout, unsigned short* __restrict__ kout,
    unsigned short* __restrict__ vout)
{
    const int t = threadIdx.x;
    const int lane = t & 63, wv = t >> 6;
    const int a = lane & 15, g = lane >> 4;

    bf16x8 wf[5][2];
    #pragma unroll
    for (int T = 0; T < 5; ++T) {
        const float* wrow;
        float scale = 1.f;
        if (T == 0) {
            if (a < 8) { wrow = Wq + a*CC; scale = LOG2E; }
            else       { wrow = Wk + (a-8)*CC; }
        } else {
            wrow = Wv + ((T-1)*16 + a)*CC;
        }
        #pragma unroll
        for (int h = 0; h < 2; ++h) {
            float4 w0 = *(const float4*)(wrow + h*32 + g*8);
            float4 w1 = *(const float4*)(wrow + h*32 + g*8 + 4);
            wf[T][h] = pack8(w0.x*scale, w0.y*scale, w0.z*scale, w0.w*scale,
                             w1.x*scale, w1.y*scale, w1.z*scale, w1.w*scale);
        }
    }
    f32x4 bias[5];
    {
        const int r = g*4;
        #pragma unroll
        for (int u = 0; u < 4; ++u) {
            int rr = r + u;
            bias[0][u] = (rr < 8) ? bq[rr]*LOG2E : bk[rr-8];
        }
        #pragma unroll
        for (int T = 1; T < 5; ++T)
            #pragma unroll
            for (int u = 0; u < 4; ++u)
                bias[T][u] = bv[(T-1)*16 + r + u];
    }

    const int wave_id = blockIdx.x*4 + wv;
    #pragma unroll 1
    for (int it = 0; it < 2; ++it) {
        const int chunk = wave_id + it*4096;
        const int b = chunk >> 11;
        const int n0 = (chunk & 2047) * 16;
        const int n = n0 + a;
        const float* xcol = x + (size_t)b*CC*NN + n;

        float xv0[8], xv1[8];
        #pragma unroll
        for (int u = 0; u < 8; ++u) xv0[u] = xcol[(size_t)(g*8 + u)*NN];
        #pragma unroll
        for (int u = 0; u < 8; ++u) xv1[u] = xcol[(size_t)(32 + g*8 + u)*NN];
        bf16x8 xb0 = pack8(xv0[0],xv0[1],xv0[2],xv0[3],xv0[4],xv0[5],xv0[6],xv0[7]);
        bf16x8 xb1 = pack8(xv1[0],xv1[1],xv1[2],xv1[3],xv1[4],xv1[5],xv1[6],xv1[7]);

        f32x4 acc[5];
        #pragma unroll
        for (int T = 0; T < 5; ++T) {
            acc[T] = __builtin_amdgcn_mfma_f32_16x16x32_bf16(wf[T][0], xb0, bias[T], 0, 0, 0);
            acc[T] = __builtin_amdgcn_mfma_f32_16x16x32_bf16(wf[T][1], xb1, acc[T], 0, 0, 0);
        }

        {
            unsigned int lo = pack_bf16(acc[0][0], acc[0][1]);
            unsigned int hi = pack_bf16(acc[0][2], acc[0][3]);
            unsigned short* base = ((g < 2) ? qout : kout) + ((size_t)b*NN + n)*8 + (g & 1)*4;
            *(int2*)base = make_int2((int)lo, (int)hi);
        }
        #pragma unroll
        for (int T = 1; T < 5; ++T) {
            #pragma unroll
            for (int u = 0; u < 4; ++u) {
                const int e = (T-1)*16 + g*4 + u;
                vout[((size_t)b*CC + e)*NN + n] = to_bf16(acc[T][u]);
            }
        }
    }
}

// ---------------- kernel 2: windowed attention, 32x32x16 MFMA, no P-LDS ----------------
// block = 4 waves; block owns (b, w, ih = half-of-window-i, ch = half-of-c).
// Wave owns 64 i x 32 c (i-width 64 keeps V-reuse; halved acc -> higher occupancy).
// Per 32-j tile:
//   E = mfma_32x32x16(K_raw, Q)  -- K hi-lane k-slots duplicate lo data but multiply
//        Q's zeroed k>=8 slots -> annihilated, no masking needed.
//   p = v_exp(E); cvt_pk pairs; v_permlane32_swap builds PV A-frag in-register.
//   acc[it] += mfma_32x32x16(P, V^T_slab)
__global__ __launch_bounds__(256, 6) void attn_kernel(
    const unsigned short* __restrict__ qg, const unsigned short* __restrict__ kg,
    const unsigned short* __restrict__ vg,
    unsigned short* __restrict__ accE, unsigned short* __restrict__ accO)
{
    __shared__ float sInv[4][2][32];
    const int t = threadIdx.x;
    const int lane = t & 63, wv = t >> 6;
    const int l31 = lane & 31, hi = lane >> 5;
    int bid = blockIdx.x;
    const int ch = bid & 1; bid >>= 1;
    const int ih = bid & 1; bid >>= 1;
    const int w = bid % NWIN, b = bid / NWIN;
    const int nwin = STR * w;
    const int i0 = ih*256 + wv*64;

    const unsigned short* qbase = qg + ((size_t)b*NN + nwin + i0)*8;
    const unsigned short* kbase = kg + ((size_t)b*NN + nwin)*8;
    const unsigned short* vbase = vg + ((size_t)b*CC + ch*32)*NN + nwin;

    const bf16x8 zf = {};
    // Q B-frags: col i = l31 (+32*it), k = d = 8*hi+e; hi half zeroed (d pad)
    bf16x8 qf[2];
    #pragma unroll
    for (int it = 0; it < 2; ++it) {
        bf16x8 raw = *(const bf16x8*)(qbase + (size_t)(it*32 + l31)*8);
        qf[it] = hi ? zf : raw;
    }
    // K A-frag for jt=0 (no masking needed: Q zeros annihilate k>=8)
    bf16x8 kc = *(const bf16x8*)(kbase + (size_t)l31*8);

    f32x16 acc[2] = {};    // [it]; cols c = ch*32 + l31
    float rsum[2] = {0.f, 0.f};

    for (int jt = 0; jt < 16; ++jt) {
        const int j0 = jt*32;
        // V^T B-frags: col c = l31 (of this wave's 32-c slab), k = j = 8*hi+e (+16*sl)
        bf16x8 vf[2];
        #pragma unroll
        for (int sl = 0; sl < 2; ++sl)
            vf[sl] = *(const bf16x8*)(vbase + (size_t)l31*NN + j0 + sl*16 + hi*8);
        // prefetch next K
        bf16x8 kn = kc;
        if (jt < 15) kn = *(const bf16x8*)(kbase + (size_t)(j0 + 32 + l31)*8);

        #pragma unroll
        for (int it = 0; it < 2; ++it) {
            const f32x16 z16 = {};
            f32x16 E = __builtin_amdgcn_mfma_f32_32x32x16_bf16(kc, qf[it], z16, 0, 0, 0);
            float p[16];
            #pragma unroll
            for (int r = 0; r < 16; ++r) p[r] = fast_exp2(E[r]);
            float s01 = (p[0]+p[1]) + (p[2]+p[3]);
            float s23 = (p[4]+p[5]) + (p[6]+p[7]);
            float s45 = (p[8]+p[9]) + (p[10]+p[11]);
            float s67 = (p[12]+p[13]) + (p[14]+p[15]);
            rsum[it] += (s01+s23) + (s45+s67);
            unsigned int wd[8];
            #pragma unroll
            for (int tw = 0; tw < 8; ++tw) wd[tw] = pack_bf16(p[2*tw], p[2*tw+1]);
            unsigned int F0 = wd[0], F2 = wd[2]; plswap(F0, F2);
            unsigned int F1 = wd[1], F3 = wd[3]; plswap(F1, F3);
            unsigned int G0 = wd[4], G2 = wd[6]; plswap(G0, G2);
            unsigned int G1 = wd[5], G3 = wd[7]; plswap(G1, G3);
            bf16x8 pa0 = words4(F0, F1, F2, F3);   // k-slab j0+0..15
            bf16x8 pa1 = words4(G0, G1, G2, G3);   // k-slab j0+16..31
            acc[it] = __builtin_amdgcn_mfma_f32_32x32x16_bf16(pa0, vf[0], acc[it], 0, 0, 0);
            acc[it] = __builtin_amdgcn_mfma_f32_32x32x16_bf16(pa1, vf[1], acc[it], 0, 0, 0);
        }
        kc = kn;
    }

    // ---- normalization: combine hi/lo j-halves, broadcast 1/r via 1KB LDS ----
    #pragma unroll
    for (int it = 0; it < 2; ++it) rsum[it] += __shfl_xor(rsum[it], 32);
    if (lane < 32) {
        sInv[wv][0][lane] = 1.f / rsum[0];
        sInv[wv][1][lane] = 1.f / rsum[1];
    }
    __builtin_amdgcn_s_waitcnt(0);   // lgkm drain before re-read (same wave wrote)
    f32x4 invv[2][4];
    #pragma unroll
    for (int it = 0; it < 2; ++it)
        #pragma unroll
        for (int g = 0; g < 4; ++g)
            invv[it][g] = *(const f32x4*)&sInv[wv][it][8*g + 4*hi];

    unsigned short* ob = ((w & 1) ? accO : accE) + ((size_t)b*CC + ch*32)*NN + nwin + i0;
    #pragma unroll
    for (int it = 0; it < 2; ++it) {
        unsigned short* cbase = ob + (size_t)l31*NN + it*32;
        #pragma unroll
        for (int g = 0; g < 4; ++g) {
            float a0 = acc[it][4*g+0] * invv[it][g][0];
            float a1 = acc[it][4*g+1] * invv[it][g][1];
            float a2 = acc[it][4*g+2] * invv[it][g][2];
            float a3 = acc[it][4*g+3] * invv[it][g][3];
            int2 pw = make_int2((int)pack_bf16(a0, a1), (int)pack_bf16(a2, a3));
            *(int2*)(cbase + 8*g + 4*hi) = pw;
        }
    }
}

// ---------------- kernel 3: combine + 2:1 maxpool ----------------
__global__ __launch_bounds__(256) void final_kernel(
    const float* __restrict__ x,
    const unsigned short* __restrict__ accE, const unsigned short* __restrict__ accO,
    const float* __restrict__ gamma, float* __restrict__ out)
{
    const size_t tid = (size_t)blockIdx.x*256 + threadIdx.x;  // B*C*N/8 threads
    const size_t base = tid*8;
    const int n = (int)(base & (NN-1));
    const float g = gamma[0];

    float xv[8];
    *(float4*)&xv[0] = *(const float4*)&x[base];
    *(float4*)&xv[4] = *(const float4*)&x[base+4];
    int4 aeq = *(const int4*)&accE[base];
    const unsigned int* ae = (const unsigned int*)&aeq;

    float s[8];
    if (n >= STR && n < NN - STR) {
        int4 aoq = *(const int4*)&accO[base];
        const unsigned int* ao = (const unsigned int*)&aoq;
        #pragma unroll
        for (int u = 0; u < 4; ++u) {
            float e0 = bf2f((unsigned short)(ae[u] & 0xffff));
            float e1 = bf2f((unsigned short)(ae[u] >> 16));
            float o0 = bf2f((unsigned short)(ao[u] & 0xffff));
            float o1 = bf2f((unsigned short)(ao[u] >> 16));
            s[2*u]   = fmaf(g, (e0 + o0)*0.5f, xv[2*u]);
            s[2*u+1] = fmaf(g, (e1 + o1)*0.5f, xv[2*u+1]);
        }
    } else {
        #pragma unroll
        for (int u = 0; u < 4; ++u) {
            float e0 = bf2f((unsigned short)(ae[u] & 0xffff));
            float e1 = bf2f((unsigned short)(ae[u] >> 16));
            s[2*u]   = fmaf(g, e0, xv[2*u]);
            s[2*u+1] = fmaf(g, e1, xv[2*u+1]);
        }
    }
    float4 o = make_float4(fmaxf(s[0], s[1]), fmaxf(s[2], s[3]),
                           fmaxf(s[4], s[5]), fmaxf(s[6], s[7]));
    *(float4*)&out[tid*4] = o;
}

extern "C" void kernel_launch(void* const* d_in, const int* in_sizes, int n_in,
                              void* d_out, int out_size, void* d_ws, size_t ws_size,
                              hipStream_t stream)
{
    const float* x    = (const float*)d_in[0];
    const float* Wq   = (const float*)d_in[1];
    const float* bq   = (const float*)d_in[2];
    const float* Wk   = (const float*)d_in[3];
    const float* bk   = (const float*)d_in[4];
    const float* Wv   = (const float*)d_in[5];
    const float* bv   = (const float*)d_in[6];
    const float* gamma= (const float*)d_in[7];

    unsigned short* q    = (unsigned short*)d_ws;
    unsigned short* k    = q + (size_t)BB*NN*DD;
    unsigned short* v    = k + (size_t)BB*NN*DD;
    unsigned short* accE = v + (size_t)BB*CC*NN;
    unsigned short* accO = accE + (size_t)BB*CC*NN;
    float* out = (float*)d_out;

    qkv_kernel<<<1024, 256, 0, stream>>>(x, Wq, bq, Wk, bk, Wv, bv, q, k, v);
    attn_kernel<<<BB*NWIN*4, 256, 0, stream>>>(q, k, v, accE, accO);
    final_kernel<<<BB*CC*NN/8/256, 256, 0, stream>>>(x, accE, accO, gamma, out);
}

// Round 10
// 103.701 us; speedup vs baseline: 2.8928x; 2.8928x over previous
//
#include <hip/hip_runtime.h>
#include <hip/hip_bf16.h>

#define BB 4
#define CC 64
#define DD 8
#define NN 32768
#define WW 512
#define STR 256
#define NWIN 127
#define LOG2E 1.4426950408889634f

typedef short bf16x8 __attribute__((ext_vector_type(8)));
typedef float f32x4 __attribute__((ext_vector_type(4)));
typedef float f32x16 __attribute__((ext_vector_type(16)));

__device__ __forceinline__ unsigned int pack_bf16(float lo, float hi) {
    __hip_bfloat162 h = __float22bfloat162_rn(make_float2(lo, hi));  // v_cvt_pk_bf16_f32
    unsigned int r; __builtin_memcpy(&r, &h, 4);
    return r;
}
__device__ __forceinline__ unsigned short to_bf16(float f) {
    __hip_bfloat16 h = __float2bfloat16(f);
    unsigned short r; __builtin_memcpy(&r, &h, 2);
    return r;
}
__device__ __forceinline__ float bf2f(unsigned short s) {
    union { unsigned int u; float f; } v; v.u = ((unsigned int)s) << 16;
    return v.f;
}
// guaranteed single v_exp_f32 (exp2f() is an ocml expansion)
__device__ __forceinline__ float fast_exp2(float x) {
#if __has_builtin(__builtin_amdgcn_exp2f)
    return __builtin_amdgcn_exp2f(x);
#else
    float r; asm("v_exp_f32 %0, %1" : "=v"(r) : "v"(x)); return r;
#endif
}
// swap upper 32 lanes of x with lower 32 lanes of y (gfx950)
__device__ __forceinline__ void plswap(unsigned int &x, unsigned int &y) {
    asm("v_permlane32_swap_b32 %0, %1" : "+v"(x), "+v"(y));
}
__device__ __forceinline__ bf16x8 pack8(float a0, float a1, float a2, float a3,
                                        float a4, float a5, float a6, float a7) {
    union { bf16x8 v; unsigned int u[4]; } r;
    r.u[0] = pack_bf16(a0, a1); r.u[1] = pack_bf16(a2, a3);
    r.u[2] = pack_bf16(a4, a5); r.u[3] = pack_bf16(a6, a7);
    return r.v;
}
__device__ __forceinline__ bf16x8 words4(unsigned int w0, unsigned int w1,
                                         unsigned int w2, unsigned int w3) {
    union { bf16x8 v; unsigned int u[4]; } r;
    r.u[0] = w0; r.u[1] = w1; r.u[2] = w2; r.u[3] = w3;
    return r.v;
}

// ---------------- kernel 1: QKV projection as MFMA GEMM ----------------
__global__ __launch_bounds__(256) void qkv_kernel(
    const float* __restrict__ x,
    const float* __restrict__ Wq, const float* __restrict__ bq,
    const float* __restrict__ Wk, const float* __restrict__ bk,
    const float* __restrict__ Wv, const float* __restrict__ bv,
    unsigned short* __restrict__ qout, unsigned short* __restrict__ kout,
    unsigned short* __restrict__ vout)
{
    const int t = threadIdx.x;
    const int lane = t & 63, wv = t >> 6;
    const int a = lane & 15, g = lane >> 4;

    bf16x8 wf[5][2];
    #pragma unroll
    for (int T = 0; T < 5; ++T) {
        const float* wrow;
        float scale = 1.f;
        if (T == 0) {
            if (a < 8) { wrow = Wq + a*CC; scale = LOG2E; }
            else       { wrow = Wk + (a-8)*CC; }
        } else {
            wrow = Wv + ((T-1)*16 + a)*CC;
        }
        #pragma unroll
        for (int h = 0; h < 2; ++h) {
            float4 w0 = *(const float4*)(wrow + h*32 + g*8);
            float4 w1 = *(const float4*)(wrow + h*32 + g*8 + 4);
            wf[T][h] = pack8(w0.x*scale, w0.y*scale, w0.z*scale, w0.w*scale,
                             w1.x*scale, w1.y*scale, w1.z*scale, w1.w*scale);
        }
    }
    f32x4 bias[5];
    {
        const int r = g*4;
        #pragma unroll
        for (int u = 0; u < 4; ++u) {
            int rr = r + u;
            bias[0][u] = (rr < 8) ? bq[rr]*LOG2E : bk[rr-8];
        }
        #pragma unroll
        for (int T = 1; T < 5; ++T)
            #pragma unroll
            for (int u = 0; u < 4; ++u)
                bias[T][u] = bv[(T-1)*16 + r + u];
    }

    const int wave_id = blockIdx.x*4 + wv;
    #pragma unroll 1
    for (int it = 0; it < 2; ++it) {
        const int chunk = wave_id + it*4096;
        const int b = chunk >> 11;
        const int n0 = (chunk & 2047) * 16;
        const int n = n0 + a;
        const float* xcol = x + (size_t)b*CC*NN + n;

        float xv0[8], xv1[8];
        #pragma unroll
        for (int u = 0; u < 8; ++u) xv0[u] = xcol[(size_t)(g*8 + u)*NN];
        #pragma unroll
        for (int u = 0; u < 8; ++u) xv1[u] = xcol[(size_t)(32 + g*8 + u)*NN];
        bf16x8 xb0 = pack8(xv0[0],xv0[1],xv0[2],xv0[3],xv0[4],xv0[5],xv0[6],xv0[7]);
        bf16x8 xb1 = pack8(xv1[0],xv1[1],xv1[2],xv1[3],xv1[4],xv1[5],xv1[6],xv1[7]);

        f32x4 acc[5];
        #pragma unroll
        for (int T = 0; T < 5; ++T) {
            acc[T] = __builtin_amdgcn_mfma_f32_16x16x32_bf16(wf[T][0], xb0, bias[T], 0, 0, 0);
            acc[T] = __builtin_amdgcn_mfma_f32_16x16x32_bf16(wf[T][1], xb1, acc[T], 0, 0, 0);
        }

        {
            unsigned int lo = pack_bf16(acc[0][0], acc[0][1]);
            unsigned int hi = pack_bf16(acc[0][2], acc[0][3]);
            unsigned short* base = ((g < 2) ? qout : kout) + ((size_t)b*NN + n)*8 + (g & 1)*4;
            *(int2*)base = make_int2((int)lo, (int)hi);
        }
        #pragma unroll
        for (int T = 1; T < 5; ++T) {
            #pragma unroll
            for (int u = 0; u < 4; ++u) {
                const int e = (T-1)*16 + g*4 + u;
                vout[((size_t)b*CC + e)*NN + n] = to_bf16(acc[T][u]);
            }
        }
    }
}

// ---------------- kernel 2: windowed attention, 32x32x16 MFMA, no P-LDS ----------------
// block = 4 waves; block owns (b, w, ih, ch); wave owns 64 i x 32 c.
// NO launch_bounds cap (R9 lesson: capping below ~110 live VGPRs -> scratch spills).
// K and V frags both prefetched one full j-tile ahead (use-distance ~300 cyc).
// XCD-aware bijective swizzle: 2032 blocks = 8 XCDs x 254; consecutive swizzled
// ids on one XCD share windows (50% V overlap) -> per-XCD L2 locality.
__global__ __launch_bounds__(256) void attn_kernel(
    const unsigned short* __restrict__ qg, const unsigned short* __restrict__ kg,
    const unsigned short* __restrict__ vg,
    unsigned short* __restrict__ accE, unsigned short* __restrict__ accO)
{
    __shared__ float sInv[4][2][32];
    const int t = threadIdx.x;
    const int lane = t & 63, wv = t >> 6;
    const int l31 = lane & 31, hi = lane >> 5;
    int bid = (blockIdx.x & 7)*254 + (blockIdx.x >> 3);   // XCD chunked swizzle
    const int ch = bid & 1; bid >>= 1;
    const int ih = bid & 1; bid >>= 1;
    const int w = bid % NWIN, b = bid / NWIN;
    const int nwin = STR * w;
    const int i0 = ih*256 + wv*64;

    const unsigned short* qbase = qg + ((size_t)b*NN + nwin + i0)*8;
    const unsigned short* kbase = kg + ((size_t)b*NN + nwin)*8;
    const unsigned short* vbase = vg + ((size_t)b*CC + ch*32)*NN + nwin;

    const bf16x8 zf = {};
    // Q B-frags: col i = l31 (+32*it), k = d = 8*hi+e; hi half zeroed (d pad)
    bf16x8 qf[2];
    #pragma unroll
    for (int it = 0; it < 2; ++it) {
        bf16x8 raw = *(const bf16x8*)(qbase + (size_t)(it*32 + l31)*8);
        qf[it] = hi ? zf : raw;
    }
    // jt=0 prefetch: K A-frag (unmasked; Q zeros annihilate k>=8) + V B-frags
    bf16x8 kc = *(const bf16x8*)(kbase + (size_t)l31*8);
    bf16x8 vc0 = *(const bf16x8*)(vbase + (size_t)l31*NN + hi*8);
    bf16x8 vc1 = *(const bf16x8*)(vbase + (size_t)l31*NN + 16 + hi*8);

    f32x16 acc[2] = {};    // [it]; cols c = ch*32 + l31
    float rsum[2] = {0.f, 0.f};

    for (int jt = 0; jt < 16; ++jt) {
        const int j0 = jt*32;
        // prefetch next tile's K + V (full-jt use distance)
        bf16x8 kn = kc, vn0 = vc0, vn1 = vc1;
        if (jt < 15) {
            kn  = *(const bf16x8*)(kbase + (size_t)(j0 + 32 + l31)*8);
            vn0 = *(const bf16x8*)(vbase + (size_t)l31*NN + j0 + 32 + hi*8);
            vn1 = *(const bf16x8*)(vbase + (size_t)l31*NN + j0 + 48 + hi*8);
        }

        #pragma unroll
        for (int it = 0; it < 2; ++it) {
            const f32x16 z16 = {};
            f32x16 E = __builtin_amdgcn_mfma_f32_32x32x16_bf16(kc, qf[it], z16, 0, 0, 0);
            float p[16];
            #pragma unroll
            for (int r = 0; r < 16; ++r) p[r] = fast_exp2(E[r]);
            float s01 = (p[0]+p[1]) + (p[2]+p[3]);
            float s23 = (p[4]+p[5]) + (p[6]+p[7]);
            float s45 = (p[8]+p[9]) + (p[10]+p[11]);
            float s67 = (p[12]+p[13]) + (p[14]+p[15]);
            rsum[it] += (s01+s23) + (s45+s67);
            unsigned int wd[8];
            #pragma unroll
            for (int tw = 0; tw < 8; ++tw) wd[tw] = pack_bf16(p[2*tw], p[2*tw+1]);
            unsigned int F0 = wd[0], F2 = wd[2]; plswap(F0, F2);
            unsigned int F1 = wd[1], F3 = wd[3]; plswap(F1, F3);
            unsigned int G0 = wd[4], G2 = wd[6]; plswap(G0, G2);
            unsigned int G1 = wd[5], G3 = wd[7]; plswap(G1, G3);
            bf16x8 pa0 = words4(F0, F1, F2, F3);   // k-slab j0+0..15
            bf16x8 pa1 = words4(G0, G1, G2, G3);   // k-slab j0+16..31
            acc[it] = __builtin_amdgcn_mfma_f32_32x32x16_bf16(pa0, vc0, acc[it], 0, 0, 0);
            acc[it] = __builtin_amdgcn_mfma_f32_32x32x16_bf16(pa1, vc1, acc[it], 0, 0, 0);
        }
        kc = kn; vc0 = vn0; vc1 = vn1;
    }

    // ---- normalization: combine hi/lo j-halves, broadcast 1/r via 1KB LDS ----
    #pragma unroll
    for (int it = 0; it < 2; ++it) rsum[it] += __shfl_xor(rsum[it], 32);
    if (lane < 32) {
        sInv[wv][0][lane] = 1.f / rsum[0];
        sInv[wv][1][lane] = 1.f / rsum[1];
    }
    f32x4 invv[2][4];
    #pragma unroll
    for (int it = 0; it < 2; ++it)
        #pragma unroll
        for (int g = 0; g < 4; ++g)
            invv[it][g] = *(const f32x4*)&sInv[wv][it][8*g + 4*hi];

    unsigned short* ob = ((w & 1) ? accO : accE) + ((size_t)b*CC + ch*32)*NN + nwin + i0;
    #pragma unroll
    for (int it = 0; it < 2; ++it) {
        unsigned short* cbase = ob + (size_t)l31*NN + it*32;
        #pragma unroll
        for (int g = 0; g < 4; ++g) {
            float a0 = acc[it][4*g+0] * invv[it][g][0];
            float a1 = acc[it][4*g+1] * invv[it][g][1];
            float a2 = acc[it][4*g+2] * invv[it][g][2];
            float a3 = acc[it][4*g+3] * invv[it][g][3];
            int2 pw = make_int2((int)pack_bf16(a0, a1), (int)pack_bf16(a2, a3));
            *(int2*)(cbase + 8*g + 4*hi) = pw;
        }
    }
}

// ---------------- kernel 3: combine + 2:1 maxpool ----------------
__global__ __launch_bounds__(256) void final_kernel(
    const float* __restrict__ x,
    const unsigned short* __restrict__ accE, const unsigned short* __restrict__ accO,
    const float* __restrict__ gamma, float* __restrict__ out)
{
    const size_t tid = (size_t)blockIdx.x*256 + threadIdx.x;  // B*C*N/8 threads
    const size_t base = tid*8;
    const int n = (int)(base & (NN-1));
    const float g = gamma[0];

    float xv[8];
    *(float4*)&xv[0] = *(const float4*)&x[base];
    *(float4*)&xv[4] = *(const float4*)&x[base+4];
    int4 aeq = *(const int4*)&accE[base];
    const unsigned int* ae = (const unsigned int*)&aeq;

    float s[8];
    if (n >= STR && n < NN - STR) {
        int4 aoq = *(const int4*)&accO[base];
        const unsigned int* ao = (const unsigned int*)&aoq;
        #pragma unroll
        for (int u = 0; u < 4; ++u) {
            float e0 = bf2f((unsigned short)(ae[u] & 0xffff));
            float e1 = bf2f((unsigned short)(ae[u] >> 16));
            float o0 = bf2f((unsigned short)(ao[u] & 0xffff));
            float o1 = bf2f((unsigned short)(ao[u] >> 16));
            s[2*u]   = fmaf(g, (e0 + o0)*0.5f, xv[2*u]);
            s[2*u+1] = fmaf(g, (e1 + o1)*0.5f, xv[2*u+1]);
        }
    } else {
        #pragma unroll
        for (int u = 0; u < 4; ++u) {
            float e0 = bf2f((unsigned short)(ae[u] & 0xffff));
            float e1 = bf2f((unsigned short)(ae[u] >> 16));
            s[2*u]   = fmaf(g, e0, xv[2*u]);
            s[2*u+1] = fmaf(g, e1, xv[2*u+1]);
        }
    }
    float4 o = make_float4(fmaxf(s[0], s[1]), fmaxf(s[2], s[3]),
                           fmaxf(s[4], s[5]), fmaxf(s[6], s[7]));
    *(float4*)&out[tid*4] = o;
}

extern "C" void kernel_launch(void* const* d_in, const int* in_sizes, int n_in,
                              void* d_out, int out_size, void* d_ws, size_t ws_size,
                              hipStream_t stream)
{
    const float* x    = (const float*)d_in[0];
    const float* Wq   = (const float*)d_in[1];
    const float* bq   = (const float*)d_in[2];
    const float* Wk   = (const float*)d_in[3];
    const float* bk   = (const float*)d_in[4];
    const float* Wv   = (const float*)d_in[5];
    const float* bv   = (const float*)d_in[6];
    const float* gamma= (const float*)d_in[7];

    unsigned short* q    = (unsigned short*)d_ws;
    unsigned short* k    = q + (size_t)BB*NN*DD;
    unsigned short* v    = k + (size_t)BB*NN*DD;
    unsigned short* accE = v + (size_t)BB*CC*NN;
    unsigned short* accO = accE + (size_t)BB*CC*NN;
    float* out = (float*)d_out;

    qkv_kernel<<<1024, 256, 0, stream>>>(x, Wq, bq, Wk, bk, Wv, bv, q, k, v);
    attn_kernel<<<BB*NWIN*4, 256, 0, stream>>>(q, k, v, accE, accO);
    final_kernel<<<BB*CC*NN/8/256, 256, 0, stream>>>(x, accE, accO, gamma, out);
}

// Round 11
// 79.864 us; speedup vs baseline: 3.7562x; 1.2985x over previous
//
#include <hip/hip_runtime.h>
#include <hip/hip_bf16.h>

#define BB 4
#define CC 64
#define DD 8
#define NN 32768
#define WW 512
#define STR 256
#define NWIN 127
#define LOG2E 1.4426950408889634f

typedef short bf16x8 __attribute__((ext_vector_type(8)));
typedef float f32x4 __attribute__((ext_vector_type(4)));
typedef float f32x16 __attribute__((ext_vector_type(16)));

__device__ __forceinline__ unsigned int pack_bf16(float lo, float hi) {
    __hip_bfloat162 h = __float22bfloat162_rn(make_float2(lo, hi));  // v_cvt_pk_bf16_f32
    unsigned int r; __builtin_memcpy(&r, &h, 4);
    return r;
}
__device__ __forceinline__ unsigned short to_bf16(float f) {
    __hip_bfloat16 h = __float2bfloat16(f);
    unsigned short r; __builtin_memcpy(&r, &h, 2);
    return r;
}
__device__ __forceinline__ float bf2f(unsigned short s) {
    union { unsigned int u; float f; } v; v.u = ((unsigned int)s) << 16;
    return v.f;
}
// guaranteed single v_exp_f32 (exp2f() is an ocml expansion)
__device__ __forceinline__ float fast_exp2(float x) {
#if __has_builtin(__builtin_amdgcn_exp2f)
    return __builtin_amdgcn_exp2f(x);
#else
    float r; asm("v_exp_f32 %0, %1" : "=v"(r) : "v"(x)); return r;
#endif
}
// swap upper 32 lanes of x with lower 32 lanes of y (gfx950)
__device__ __forceinline__ void plswap(unsigned int &x, unsigned int &y) {
    asm("v_permlane32_swap_b32 %0, %1" : "+v"(x), "+v"(y));
}
__device__ __forceinline__ bf16x8 pack8(float a0, float a1, float a2, float a3,
                                        float a4, float a5, float a6, float a7) {
    union { bf16x8 v; unsigned int u[4]; } r;
    r.u[0] = pack_bf16(a0, a1); r.u[1] = pack_bf16(a2, a3);
    r.u[2] = pack_bf16(a4, a5); r.u[3] = pack_bf16(a6, a7);
    return r.v;
}
__device__ __forceinline__ bf16x8 words4(unsigned int w0, unsigned int w1,
                                         unsigned int w2, unsigned int w3) {
    union { bf16x8 v; unsigned int u[4]; } r;
    r.u[0] = w0; r.u[1] = w1; r.u[2] = w2; r.u[3] = w3;
    return r.v;
}

// ---------------- kernel 1: QKV projection as MFMA GEMM ----------------
__global__ __launch_bounds__(256) void qkv_kernel(
    const float* __restrict__ x,
    const float* __restrict__ Wq, const float* __restrict__ bq,
    const float* __restrict__ Wk, const float* __restrict__ bk,
    const float* __restrict__ Wv, const float* __restrict__ bv,
    unsigned short* __restrict__ qout, unsigned short* __restrict__ kout,
    unsigned short* __restrict__ vout)
{
    const int t = threadIdx.x;
    const int lane = t & 63, wv = t >> 6;
    const int a = lane & 15, g = lane >> 4;

    bf16x8 wf[5][2];
    #pragma unroll
    for (int T = 0; T < 5; ++T) {
        const float* wrow;
        float scale = 1.f;
        if (T == 0) {
            if (a < 8) { wrow = Wq + a*CC; scale = LOG2E; }
            else       { wrow = Wk + (a-8)*CC; }
        } else {
            wrow = Wv + ((T-1)*16 + a)*CC;
        }
        #pragma unroll
        for (int h = 0; h < 2; ++h) {
            float4 w0 = *(const float4*)(wrow + h*32 + g*8);
            float4 w1 = *(const float4*)(wrow + h*32 + g*8 + 4);
            wf[T][h] = pack8(w0.x*scale, w0.y*scale, w0.z*scale, w0.w*scale,
                             w1.x*scale, w1.y*scale, w1.z*scale, w1.w*scale);
        }
    }
    f32x4 bias[5];
    {
        const int r = g*4;
        #pragma unroll
        for (int u = 0; u < 4; ++u) {
            int rr = r + u;
            bias[0][u] = (rr < 8) ? bq[rr]*LOG2E : bk[rr-8];
        }
        #pragma unroll
        for (int T = 1; T < 5; ++T)
            #pragma unroll
            for (int u = 0; u < 4; ++u)
                bias[T][u] = bv[(T-1)*16 + r + u];
    }

    const int wave_id = blockIdx.x*4 + wv;
    #pragma unroll 1
    for (int it = 0; it < 2; ++it) {
        const int chunk = wave_id + it*4096;
        const int b = chunk >> 11;
        const int n0 = (chunk & 2047) * 16;
        const int n = n0 + a;
        const float* xcol = x + (size_t)b*CC*NN + n;

        float xv0[8], xv1[8];
        #pragma unroll
        for (int u = 0; u < 8; ++u) xv0[u] = xcol[(size_t)(g*8 + u)*NN];
        #pragma unroll
        for (int u = 0; u < 8; ++u) xv1[u] = xcol[(size_t)(32 + g*8 + u)*NN];
        bf16x8 xb0 = pack8(xv0[0],xv0[1],xv0[2],xv0[3],xv0[4],xv0[5],xv0[6],xv0[7]);
        bf16x8 xb1 = pack8(xv1[0],xv1[1],xv1[2],xv1[3],xv1[4],xv1[5],xv1[6],xv1[7]);

        f32x4 acc[5];
        #pragma unroll
        for (int T = 0; T < 5; ++T) {
            acc[T] = __builtin_amdgcn_mfma_f32_16x16x32_bf16(wf[T][0], xb0, bias[T], 0, 0, 0);
            acc[T] = __builtin_amdgcn_mfma_f32_16x16x32_bf16(wf[T][1], xb1, acc[T], 0, 0, 0);
        }

        {
            unsigned int lo = pack_bf16(acc[0][0], acc[0][1]);
            unsigned int hi = pack_bf16(acc[0][2], acc[0][3]);
            unsigned short* base = ((g < 2) ? qout : kout) + ((size_t)b*NN + n)*8 + (g & 1)*4;
            *(int2*)base = make_int2((int)lo, (int)hi);
        }
        #pragma unroll
        for (int T = 1; T < 5; ++T) {
            #pragma unroll
            for (int u = 0; u < 4; ++u) {
                const int e = (T-1)*16 + g*4 + u;
                vout[((size_t)b*CC + e)*NN + n] = to_bf16(acc[T][u]);
            }
        }
    }
}

// ---------------- kernel 2: windowed attention, 32x32x16 MFMA, no P-LDS ----------------
// R8 geometry: block = 4 waves = (b, w, ih); wave owns 64 i x 64 c (E shared
// across all 64 c -- the exp-efficiency sweet spot). No launch_bounds cap.
// + XCD bijective swizzle (1016 = 8 x 127): adjacent swizzled ids on one XCD
//   share the window K/V -> L2/L3 hits instead of ~900-cyc HBM misses (R10 data).
// + float2 rowsum tree (v_pk_add_f32 candidate), s_setprio around MFMA cluster.
__global__ __launch_bounds__(256) void attn_kernel(
    const unsigned short* __restrict__ qg, const unsigned short* __restrict__ kg,
    const unsigned short* __restrict__ vg,
    unsigned short* __restrict__ accE, unsigned short* __restrict__ accO)
{
    __shared__ float sInv[4][2][32];
    const int t = threadIdx.x;
    const int lane = t & 63, wv = t >> 6;
    const int l31 = lane & 31, hi = lane >> 5;
    int bid = (blockIdx.x & 7)*127 + (blockIdx.x >> 3);   // XCD chunked swizzle (8x127)
    const int ih = bid & 1; bid >>= 1;
    const int w = bid % NWIN, b = bid / NWIN;
    const int nwin = STR * w;
    const int i0 = ih*256 + wv*64;

    const unsigned short* qbase = qg + ((size_t)b*NN + nwin + i0)*8;
    const unsigned short* kbase = kg + ((size_t)b*NN + nwin)*8;
    const unsigned short* vbase = vg + (size_t)b*CC*NN + nwin;

    const bf16x8 zf = {};
    // Q B-frags: col i = l31 (+32*it), k = d = 8*hi+e; hi half zeroed (d pad)
    bf16x8 qf[2];
    #pragma unroll
    for (int it = 0; it < 2; ++it) {
        bf16x8 raw = *(const bf16x8*)(qbase + (size_t)(it*32 + l31)*8);
        qf[it] = hi ? zf : raw;
    }
    // K A-frag for jt=0 (unmasked: Q zeros annihilate k>=8 garbage)
    bf16x8 kc = *(const bf16x8*)(kbase + (size_t)l31*8);

    f32x16 acc[2][2] = {};    // [it][ct]
    float2 rsum2[2] = {make_float2(0.f,0.f), make_float2(0.f,0.f)};

    for (int jt = 0; jt < 16; ++jt) {
        const int j0 = jt*32;
        // V^T B-frags for THIS tile at body top (compiler issues early; ~full-body
        // use distance covers L2 latency). col c = ct*32+l31, k = j = 8*hi+e+16*sl
        bf16x8 vf[2][2];
        #pragma unroll
        for (int ct = 0; ct < 2; ++ct)
            #pragma unroll
            for (int sl = 0; sl < 2; ++sl)
                vf[ct][sl] = *(const bf16x8*)(vbase + (size_t)(ct*32 + l31)*NN + j0 + sl*16 + hi*8);
        // 1-deep K prefetch
        bf16x8 kn = kc;
        if (jt < 15) kn = *(const bf16x8*)(kbase + (size_t)(j0 + 32 + l31)*8);

        #pragma unroll
        for (int it = 0; it < 2; ++it) {
            __builtin_amdgcn_s_setprio(1);
            const f32x16 z16 = {};
            f32x16 E = __builtin_amdgcn_mfma_f32_32x32x16_bf16(kc, qf[it], z16, 0, 0, 0);
            float p[16];
            #pragma unroll
            for (int r = 0; r < 16; ++r) p[r] = fast_exp2(E[r]);
            // rowsum as float2 tree (packed-add candidate)
            float2 s0 = make_float2(p[0],  p[1])  + make_float2(p[2],  p[3]);
            float2 s1 = make_float2(p[4],  p[5])  + make_float2(p[6],  p[7]);
            float2 s2 = make_float2(p[8],  p[9])  + make_float2(p[10], p[11]);
            float2 s3 = make_float2(p[12], p[13]) + make_float2(p[14], p[15]);
            rsum2[it] += (s0 + s1) + (s2 + s3);
            unsigned int wd[8];
            #pragma unroll
            for (int tw = 0; tw < 8; ++tw) wd[tw] = pack_bf16(p[2*tw], p[2*tw+1]);
            unsigned int F0 = wd[0], F2 = wd[2]; plswap(F0, F2);
            unsigned int F1 = wd[1], F3 = wd[3]; plswap(F1, F3);
            unsigned int G0 = wd[4], G2 = wd[6]; plswap(G0, G2);
            unsigned int G1 = wd[5], G3 = wd[7]; plswap(G1, G3);
            bf16x8 pa0 = words4(F0, F1, F2, F3);   // k-slab j0+0..15
            bf16x8 pa1 = words4(G0, G1, G2, G3);   // k-slab j0+16..31
            #pragma unroll
            for (int ct = 0; ct < 2; ++ct) {
                acc[it][ct] = __builtin_amdgcn_mfma_f32_32x32x16_bf16(pa0, vf[ct][0], acc[it][ct], 0, 0, 0);
                acc[it][ct] = __builtin_amdgcn_mfma_f32_32x32x16_bf16(pa1, vf[ct][1], acc[it][ct], 0, 0, 0);
            }
            __builtin_amdgcn_s_setprio(0);
        }
        kc = kn;
    }

    // ---- normalization: combine hi/lo j-halves, broadcast 1/r via 1KB LDS ----
    float rsum[2];
    #pragma unroll
    for (int it = 0; it < 2; ++it) {
        float r = rsum2[it].x + rsum2[it].y;
        r += __shfl_xor(r, 32);
        rsum[it] = r;
    }
    if (lane < 32) {
        sInv[wv][0][lane] = 1.f / rsum[0];
        sInv[wv][1][lane] = 1.f / rsum[1];
    }
    f32x4 invv[2][4];
    #pragma unroll
    for (int it = 0; it < 2; ++it)
        #pragma unroll
        for (int g = 0; g < 4; ++g)
            invv[it][g] = *(const f32x4*)&sInv[wv][it][8*g + 4*hi];

    unsigned short* ob = ((w & 1) ? accO : accE) + (size_t)b*CC*NN + nwin + i0;
    #pragma unroll
    for (int it = 0; it < 2; ++it) {
        #pragma unroll
        for (int ct = 0; ct < 2; ++ct) {
            unsigned short* cbase = ob + (size_t)(ct*32 + l31)*NN + it*32;
            #pragma unroll
            for (int g = 0; g < 4; ++g) {
                float a0 = acc[it][ct][4*g+0] * invv[it][g][0];
                float a1 = acc[it][ct][4*g+1] * invv[it][g][1];
                float a2 = acc[it][ct][4*g+2] * invv[it][g][2];
                float a3 = acc[it][ct][4*g+3] * invv[it][g][3];
                int2 pw = make_int2((int)pack_bf16(a0, a1), (int)pack_bf16(a2, a3));
                *(int2*)(cbase + 8*g + 4*hi) = pw;
            }
        }
    }
}

// ---------------- kernel 3: combine + 2:1 maxpool ----------------
__global__ __launch_bounds__(256) void final_kernel(
    const float* __restrict__ x,
    const unsigned short* __restrict__ accE, const unsigned short* __restrict__ accO,
    const float* __restrict__ gamma, float* __restrict__ out)
{
    const size_t tid = (size_t)blockIdx.x*256 + threadIdx.x;  // B*C*N/8 threads
    const size_t base = tid*8;
    const int n = (int)(base & (NN-1));
    const float g = gamma[0];

    float xv[8];
    *(float4*)&xv[0] = *(const float4*)&x[base];
    *(float4*)&xv[4] = *(const float4*)&x[base+4];
    int4 aeq = *(const int4*)&accE[base];
    const unsigned int* ae = (const unsigned int*)&aeq;

    float s[8];
    if (n >= STR && n < NN - STR) {
        int4 aoq = *(const int4*)&accO[base];
        const unsigned int* ao = (const unsigned int*)&aoq;
        #pragma unroll
        for (int u = 0; u < 4; ++u) {
            float e0 = bf2f((unsigned short)(ae[u] & 0xffff));
            float e1 = bf2f((unsigned short)(ae[u] >> 16));
            float o0 = bf2f((unsigned short)(ao[u] & 0xffff));
            float o1 = bf2f((unsigned short)(ao[u] >> 16));
            s[2*u]   = fmaf(g, (e0 + o0)*0.5f, xv[2*u]);
            s[2*u+1] = fmaf(g, (e1 + o1)*0.5f, xv[2*u+1]);
        }
    } else {
        #pragma unroll
        for (int u = 0; u < 4; ++u) {
            float e0 = bf2f((unsigned short)(ae[u] & 0xffff));
            float e1 = bf2f((unsigned short)(ae[u] >> 16));
            s[2*u]   = fmaf(g, e0, xv[2*u]);
            s[2*u+1] = fmaf(g, e1, xv[2*u+1]);
        }
    }
    float4 o = make_float4(fmaxf(s[0], s[1]), fmaxf(s[2], s[3]),
                           fmaxf(s[4], s[5]), fmaxf(s[6], s[7]));
    *(float4*)&out[tid*4] = o;
}

extern "C" void kernel_launch(void* const* d_in, const int* in_sizes, int n_in,
                              void* d_out, int out_size, void* d_ws, size_t ws_size,
                              hipStream_t stream)
{
    const float* x    = (const float*)d_in[0];
    const float* Wq   = (const float*)d_in[1];
    const float* bq   = (const float*)d_in[2];
    const float* Wk   = (const float*)d_in[3];
    const float* bk   = (const float*)d_in[4];
    const float* Wv   = (const float*)d_in[5];
    const float* bv   = (const float*)d_in[6];
    const float* gamma= (const float*)d_in[7];

    unsigned short* q    = (unsigned short*)d_ws;
    unsigned short* k    = q + (size_t)BB*NN*DD;
    unsigned short* v    = k + (size_t)BB*NN*DD;
    unsigned short* accE = v + (size_t)BB*CC*NN;
    unsigned short* accO = accE + (size_t)BB*CC*NN;
    float* out = (float*)d_out;

    qkv_kernel<<<1024, 256, 0, stream>>>(x, Wq, bq, Wk, bk, Wv, bv, q, k, v);
    attn_kernel<<<BB*NWIN*2, 256, 0, stream>>>(q, k, v, accE, accO);
    final_kernel<<<BB*CC*NN/8/256, 256, 0, stream>>>(x, accE, accO, gamma, out);
}

// Round 12
// 78.639 us; speedup vs baseline: 3.8147x; 1.0156x over previous
//
#include <hip/hip_runtime.h>
#include <hip/hip_bf16.h>

#define BB 4
#define CC 64
#define DD 8
#define NN 32768
#define WW 512
#define STR 256
#define NWIN 127
#define LOG2E 1.4426950408889634f

typedef short bf16x8 __attribute__((ext_vector_type(8)));
typedef float f32x4 __attribute__((ext_vector_type(4)));
typedef float f32x16 __attribute__((ext_vector_type(16)));

__device__ __forceinline__ unsigned int pack_bf16(float lo, float hi) {
    __hip_bfloat162 h = __float22bfloat162_rn(make_float2(lo, hi));  // v_cvt_pk_bf16_f32
    unsigned int r; __builtin_memcpy(&r, &h, 4);
    return r;
}
__device__ __forceinline__ unsigned short to_bf16(float f) {
    __hip_bfloat16 h = __float2bfloat16(f);
    unsigned short r; __builtin_memcpy(&r, &h, 2);
    return r;
}
__device__ __forceinline__ float bf2f(unsigned short s) {
    union { unsigned int u; float f; } v; v.u = ((unsigned int)s) << 16;
    return v.f;
}
// guaranteed single v_exp_f32 (exp2f() is an ocml expansion)
__device__ __forceinline__ float fast_exp2(float x) {
#if __has_builtin(__builtin_amdgcn_exp2f)
    return __builtin_amdgcn_exp2f(x);
#else
    float r; asm("v_exp_f32 %0, %1" : "=v"(r) : "v"(x)); return r;
#endif
}
// swap upper 32 lanes of x with lower 32 lanes of y (gfx950)
__device__ __forceinline__ void plswap(unsigned int &x, unsigned int &y) {
    asm("v_permlane32_swap_b32 %0, %1" : "+v"(x), "+v"(y));
}
__device__ __forceinline__ bf16x8 pack8(float a0, float a1, float a2, float a3,
                                        float a4, float a5, float a6, float a7) {
    union { bf16x8 v; unsigned int u[4]; } r;
    r.u[0] = pack_bf16(a0, a1); r.u[1] = pack_bf16(a2, a3);
    r.u[2] = pack_bf16(a4, a5); r.u[3] = pack_bf16(a6, a7);
    return r.v;
}
__device__ __forceinline__ bf16x8 words4(unsigned int w0, unsigned int w1,
                                         unsigned int w2, unsigned int w3) {
    union { bf16x8 v; unsigned int u[4]; } r;
    r.u[0] = w0; r.u[1] = w1; r.u[2] = w2; r.u[3] = w3;
    return r.v;
}

// ---------------- kernel 1: QKV projection as MFMA GEMM ----------------
__global__ __launch_bounds__(256) void qkv_kernel(
    const float* __restrict__ x,
    const float* __restrict__ Wq, const float* __restrict__ bq,
    const float* __restrict__ Wk, const float* __restrict__ bk,
    const float* __restrict__ Wv, const float* __restrict__ bv,
    unsigned short* __restrict__ qout, unsigned short* __restrict__ kout,
    unsigned short* __restrict__ vout)
{
    const int t = threadIdx.x;
    const int lane = t & 63, wv = t >> 6;
    const int a = lane & 15, g = lane >> 4;

    bf16x8 wf[5][2];
    #pragma unroll
    for (int T = 0; T < 5; ++T) {
        const float* wrow;
        float scale = 1.f;
        if (T == 0) {
            if (a < 8) { wrow = Wq + a*CC; scale = LOG2E; }
            else       { wrow = Wk + (a-8)*CC; }
        } else {
            wrow = Wv + ((T-1)*16 + a)*CC;
        }
        #pragma unroll
        for (int h = 0; h < 2; ++h) {
            float4 w0 = *(const float4*)(wrow + h*32 + g*8);
            float4 w1 = *(const float4*)(wrow + h*32 + g*8 + 4);
            wf[T][h] = pack8(w0.x*scale, w0.y*scale, w0.z*scale, w0.w*scale,
                             w1.x*scale, w1.y*scale, w1.z*scale, w1.w*scale);
        }
    }
    f32x4 bias[5];
    {
        const int r = g*4;
        #pragma unroll
        for (int u = 0; u < 4; ++u) {
            int rr = r + u;
            bias[0][u] = (rr < 8) ? bq[rr]*LOG2E : bk[rr-8];
        }
        #pragma unroll
        for (int T = 1; T < 5; ++T)
            #pragma unroll
            for (int u = 0; u < 4; ++u)
                bias[T][u] = bv[(T-1)*16 + r + u];
    }

    const int wave_id = blockIdx.x*4 + wv;
    #pragma unroll 1
    for (int it = 0; it < 2; ++it) {
        const int chunk = wave_id + it*4096;
        const int b = chunk >> 11;
        const int n0 = (chunk & 2047) * 16;
        const int n = n0 + a;
        const float* xcol = x + (size_t)b*CC*NN + n;

        float xv0[8], xv1[8];
        #pragma unroll
        for (int u = 0; u < 8; ++u) xv0[u] = xcol[(size_t)(g*8 + u)*NN];
        #pragma unroll
        for (int u = 0; u < 8; ++u) xv1[u] = xcol[(size_t)(32 + g*8 + u)*NN];
        bf16x8 xb0 = pack8(xv0[0],xv0[1],xv0[2],xv0[3],xv0[4],xv0[5],xv0[6],xv0[7]);
        bf16x8 xb1 = pack8(xv1[0],xv1[1],xv1[2],xv1[3],xv1[4],xv1[5],xv1[6],xv1[7]);

        f32x4 acc[5];
        #pragma unroll
        for (int T = 0; T < 5; ++T) {
            acc[T] = __builtin_amdgcn_mfma_f32_16x16x32_bf16(wf[T][0], xb0, bias[T], 0, 0, 0);
            acc[T] = __builtin_amdgcn_mfma_f32_16x16x32_bf16(wf[T][1], xb1, acc[T], 0, 0, 0);
        }

        {
            unsigned int lo = pack_bf16(acc[0][0], acc[0][1]);
            unsigned int hi = pack_bf16(acc[0][2], acc[0][3]);
            unsigned short* base = ((g < 2) ? qout : kout) + ((size_t)b*NN + n)*8 + (g & 1)*4;
            *(int2*)base = make_int2((int)lo, (int)hi);
        }
        #pragma unroll
        for (int T = 1; T < 5; ++T) {
            #pragma unroll
            for (int u = 0; u < 4; ++u) {
                const int e = (T-1)*16 + g*4 + u;
                vout[((size_t)b*CC + e)*NN + n] = to_bf16(acc[T][u]);
            }
        }
    }
}

// ---------------- kernel 2: windowed attention, 32x32x16 MFMA ----------------
// R8 geometry (wave = 64i x 64c) + LDS data movement:
//  - K window (512x16B = 8KB) staged ONCE, coalesced; per-jt ds_read_b128.
//  - V tile (32j x 64c = 4KB) staged per jt, double-buffered, coalesced 64B rows;
//    LDS rows padded to 72B -> all frag reads are 2x ds_read_b64 at <=2-way banks.
//  - One __syncthreads per jt; global V transactions per block-jt: 512 -> 64.
// Compute per jt unchanged: E=mfma(K,Q); exp2; cvt_pk; permlane32_swap; PV mfma.
__global__ __launch_bounds__(256) void attn_kernel(
    const unsigned short* __restrict__ qg, const unsigned short* __restrict__ kg,
    const unsigned short* __restrict__ vg,
    unsigned short* __restrict__ accE, unsigned short* __restrict__ accO)
{
    __shared__ unsigned short sK[WW][8];        // 8 KB, [j][d]
    __shared__ unsigned short sV[2][64][36];    // 2 x 4.5 KB, [c][j-local], 72B rows
    __shared__ float sInv[4][2][32];
    const int t = threadIdx.x;
    const int lane = t & 63, wv = t >> 6;
    const int l31 = lane & 31, hi = lane >> 5;
    int bid = (blockIdx.x & 7)*127 + (blockIdx.x >> 3);   // XCD bijective swizzle (8x127)
    const int ih = bid & 1; bid >>= 1;
    const int w = bid % NWIN, b = bid / NWIN;
    const int nwin = STR * w;
    const int i0 = ih*256 + wv*64;

    const unsigned short* qbase = qg + ((size_t)b*NN + nwin + i0)*8;
    const unsigned short* kbase = kg + ((size_t)b*NN + nwin)*8;
    const unsigned short* vsrc  = vg + ((size_t)b*CC + (t >> 2))*NN + nwin + (t & 3)*8;

    // ---- stage K window (coalesced, 2 x 16B per thread) ----
    #pragma unroll
    for (int m = 0; m < 2; ++m) {
        const int row = m*256 + t;
        *(int4*)&sK[row][0] = *(const int4*)(kbase + (size_t)row*8);
    }
    // ---- stage V tile jt=0 ----
    {
        int4 r = *(const int4*)vsrc;
        unsigned short* dst = &sV[0][t >> 2][(t & 3)*8];
        *(int2*)dst = *(int2*)&r;
        *(int2*)(dst + 4) = *((int2*)&r + 1);
    }

    const bf16x8 zf = {};
    // Q B-frags: col i = l31 (+32*it), k = d; hi half zeroed (d pad annihilates)
    bf16x8 qf[2];
    #pragma unroll
    for (int it = 0; it < 2; ++it) {
        bf16x8 raw = *(const bf16x8*)(qbase + (size_t)(it*32 + l31)*8);
        qf[it] = hi ? zf : raw;
    }

    f32x16 acc[2][2] = {};    // [it][ct]
    float2 rsum2[2] = {make_float2(0.f,0.f), make_float2(0.f,0.f)};

    __syncthreads();

    for (int jt = 0; jt < 16; ++jt) {
        const int j0 = jt*32;
        const int cur = jt & 1;
        // issue next tile's global V loads first (hide under compute)
        int4 stg;
        if (jt < 15) stg = *(const int4*)(vsrc + j0 + 32);

        // K frag from LDS (hi lanes broadcast row; Q zeros annihilate k>=8)
        bf16x8 kc = *(const bf16x8*)&sK[j0 + l31][0];
        // V frags from LDS: c = ct*32+l31, j-local = sl*16 + hi*8 (2x b64 each)
        bf16x8 vf[2][2];
        #pragma unroll
        for (int ct = 0; ct < 2; ++ct)
            #pragma unroll
            for (int sl = 0; sl < 2; ++sl) {
                const unsigned short* p = &sV[cur][ct*32 + l31][sl*16 + hi*8];
                union { bf16x8 v; int2 d[2]; } u;
                u.d[0] = *(const int2*)p;
                u.d[1] = *(const int2*)(p + 4);
                vf[ct][sl] = u.v;
            }

        #pragma unroll
        for (int it = 0; it < 2; ++it) {
            const f32x16 z16 = {};
            f32x16 E = __builtin_amdgcn_mfma_f32_32x32x16_bf16(kc, qf[it], z16, 0, 0, 0);
            float p[16];
            #pragma unroll
            for (int r = 0; r < 16; ++r) p[r] = fast_exp2(E[r]);
            float2 s0 = make_float2(p[0],  p[1])  + make_float2(p[2],  p[3]);
            float2 s1 = make_float2(p[4],  p[5])  + make_float2(p[6],  p[7]);
            float2 s2 = make_float2(p[8],  p[9])  + make_float2(p[10], p[11]);
            float2 s3 = make_float2(p[12], p[13]) + make_float2(p[14], p[15]);
            rsum2[it] += (s0 + s1) + (s2 + s3);
            unsigned int wd[8];
            #pragma unroll
            for (int tw = 0; tw < 8; ++tw) wd[tw] = pack_bf16(p[2*tw], p[2*tw+1]);
            unsigned int F0 = wd[0], F2 = wd[2]; plswap(F0, F2);
            unsigned int F1 = wd[1], F3 = wd[3]; plswap(F1, F3);
            unsigned int G0 = wd[4], G2 = wd[6]; plswap(G0, G2);
            unsigned int G1 = wd[5], G3 = wd[7]; plswap(G1, G3);
            bf16x8 pa0 = words4(F0, F1, F2, F3);   // k-slab j0+0..15
            bf16x8 pa1 = words4(G0, G1, G2, G3);   // k-slab j0+16..31
            #pragma unroll
            for (int ct = 0; ct < 2; ++ct) {
                acc[it][ct] = __builtin_amdgcn_mfma_f32_32x32x16_bf16(pa0, vf[ct][0], acc[it][ct], 0, 0, 0);
                acc[it][ct] = __builtin_amdgcn_mfma_f32_32x32x16_bf16(pa1, vf[ct][1], acc[it][ct], 0, 0, 0);
            }
        }

        // write next tile into the other buffer, then sync
        if (jt < 15) {
            unsigned short* dst = &sV[cur ^ 1][t >> 2][(t & 3)*8];
            *(int2*)dst = *(int2*)&stg;
            *(int2*)(dst + 4) = *((int2*)&stg + 1);
        }
        __syncthreads();
    }

    // ---- normalization: combine hi/lo j-halves, broadcast 1/r via 1KB LDS ----
    float rsum[2];
    #pragma unroll
    for (int it = 0; it < 2; ++it) {
        float r = rsum2[it].x + rsum2[it].y;
        r += __shfl_xor(r, 32);
        rsum[it] = r;
    }
    if (lane < 32) {
        sInv[wv][0][lane] = 1.f / rsum[0];
        sInv[wv][1][lane] = 1.f / rsum[1];
    }
    f32x4 invv[2][4];
    #pragma unroll
    for (int it = 0; it < 2; ++it)
        #pragma unroll
        for (int g = 0; g < 4; ++g)
            invv[it][g] = *(const f32x4*)&sInv[wv][it][8*g + 4*hi];

    unsigned short* ob = ((w & 1) ? accO : accE) + (size_t)b*CC*NN + nwin + i0;
    #pragma unroll
    for (int it = 0; it < 2; ++it) {
        #pragma unroll
        for (int ct = 0; ct < 2; ++ct) {
            unsigned short* cbase = ob + (size_t)(ct*32 + l31)*NN + it*32;
            #pragma unroll
            for (int g = 0; g < 4; ++g) {
                float a0 = acc[it][ct][4*g+0] * invv[it][g][0];
                float a1 = acc[it][ct][4*g+1] * invv[it][g][1];
                float a2 = acc[it][ct][4*g+2] * invv[it][g][2];
                float a3 = acc[it][ct][4*g+3] * invv[it][g][3];
                int2 pw = make_int2((int)pack_bf16(a0, a1), (int)pack_bf16(a2, a3));
                *(int2*)(cbase + 8*g + 4*hi) = pw;
            }
        }
    }
}

// ---------------- kernel 3: combine + 2:1 maxpool ----------------
__global__ __launch_bounds__(256) void final_kernel(
    const float* __restrict__ x,
    const unsigned short* __restrict__ accE, const unsigned short* __restrict__ accO,
    const float* __restrict__ gamma, float* __restrict__ out)
{
    const size_t tid = (size_t)blockIdx.x*256 + threadIdx.x;  // B*C*N/8 threads
    const size_t base = tid*8;
    const int n = (int)(base & (NN-1));
    const float g = gamma[0];

    float xv[8];
    *(float4*)&xv[0] = *(const float4*)&x[base];
    *(float4*)&xv[4] = *(const float4*)&x[base+4];
    int4 aeq = *(const int4*)&accE[base];
    const unsigned int* ae = (const unsigned int*)&aeq;

    float s[8];
    if (n >= STR && n < NN - STR) {
        int4 aoq = *(const int4*)&accO[base];
        const unsigned int* ao = (const unsigned int*)&aoq;
        #pragma unroll
        for (int u = 0; u < 4; ++u) {
            float e0 = bf2f((unsigned short)(ae[u] & 0xffff));
            float e1 = bf2f((unsigned short)(ae[u] >> 16));
            float o0 = bf2f((unsigned short)(ao[u] & 0xffff));
            float o1 = bf2f((unsigned short)(ao[u] >> 16));
            s[2*u]   = fmaf(g, (e0 + o0)*0.5f, xv[2*u]);
            s[2*u+1] = fmaf(g, (e1 + o1)*0.5f, xv[2*u+1]);
        }
    } else {
        #pragma unroll
        for (int u = 0; u < 4; ++u) {
            float e0 = bf2f((unsigned short)(ae[u] & 0xffff));
            float e1 = bf2f((unsigned short)(ae[u] >> 16));
            s[2*u]   = fmaf(g, e0, xv[2*u]);
            s[2*u+1] = fmaf(g, e1, xv[2*u+1]);
        }
    }
    float4 o = make_float4(fmaxf(s[0], s[1]), fmaxf(s[2], s[3]),
                           fmaxf(s[4], s[5]), fmaxf(s[6], s[7]));
    *(float4*)&out[tid*4] = o;
}

extern "C" void kernel_launch(void* const* d_in, const int* in_sizes, int n_in,
                              void* d_out, int out_size, void* d_ws, size_t ws_size,
                              hipStream_t stream)
{
    const float* x    = (const float*)d_in[0];
    const float* Wq   = (const float*)d_in[1];
    const float* bq   = (const float*)d_in[2];
    const float* Wk   = (const float*)d_in[3];
    const float* bk   = (const float*)d_in[4];
    const float* Wv   = (const float*)d_in[5];
    const float* bv   = (const float*)d_in[6];
    const float* gamma= (const float*)d_in[7];

    unsigned short* q    = (unsigned short*)d_ws;
    unsigned short* k    = q + (size_t)BB*NN*DD;
    unsigned short* v    = k + (size_t)BB*NN*DD;
    unsigned short* accE = v + (size_t)BB*CC*NN;
    unsigned short* accO = accE + (size_t)BB*CC*NN;
    float* out = (float*)d_out;

    qkv_kernel<<<1024, 256, 0, stream>>>(x, Wq, bq, Wk, bk, Wv, bv, q, k, v);
    attn_kernel<<<BB*NWIN*2, 256, 0, stream>>>(q, k, v, accE, accO);
    final_kernel<<<BB*CC*NN/8/256, 256, 0, stream>>>(x, accE, accO, gamma, out);
}

// Round 13
// 73.443 us; speedup vs baseline: 4.0846x; 1.0708x over previous
//
#include <hip/hip_runtime.h>
#include <hip/hip_bf16.h>

#define BB 4
#define CC 64
#define DD 8
#define NN 32768
#define WW 512
#define STR 256
#define NWIN 127
#define LOG2E 1.4426950408889634f

typedef short bf16x8 __attribute__((ext_vector_type(8)));
typedef float f32x4 __attribute__((ext_vector_type(4)));
typedef float f32x16 __attribute__((ext_vector_type(16)));

__device__ __forceinline__ unsigned int pack_bf16(float lo, float hi) {
    __hip_bfloat162 h = __float22bfloat162_rn(make_float2(lo, hi));  // v_cvt_pk_bf16_f32
    unsigned int r; __builtin_memcpy(&r, &h, 4);
    return r;
}
__device__ __forceinline__ unsigned short to_bf16(float f) {
    __hip_bfloat16 h = __float2bfloat16(f);
    unsigned short r; __builtin_memcpy(&r, &h, 2);
    return r;
}
__device__ __forceinline__ float bf2f(unsigned short s) {
    union { unsigned int u; float f; } v; v.u = ((unsigned int)s) << 16;
    return v.f;
}
// guaranteed single v_exp_f32 (exp2f() is an ocml expansion)
__device__ __forceinline__ float fast_exp2(float x) {
#if __has_builtin(__builtin_amdgcn_exp2f)
    return __builtin_amdgcn_exp2f(x);
#else
    float r; asm("v_exp_f32 %0, %1" : "=v"(r) : "v"(x)); return r;
#endif
}
// swap upper 32 lanes of x with lower 32 lanes of y (gfx950)
__device__ __forceinline__ void plswap(unsigned int &x, unsigned int &y) {
    asm("v_permlane32_swap_b32 %0, %1" : "+v"(x), "+v"(y));
}
__device__ __forceinline__ bf16x8 pack8(float a0, float a1, float a2, float a3,
                                        float a4, float a5, float a6, float a7) {
    union { bf16x8 v; unsigned int u[4]; } r;
    r.u[0] = pack_bf16(a0, a1); r.u[1] = pack_bf16(a2, a3);
    r.u[2] = pack_bf16(a4, a5); r.u[3] = pack_bf16(a6, a7);
    return r.v;
}
__device__ __forceinline__ bf16x8 words4(unsigned int w0, unsigned int w1,
                                         unsigned int w2, unsigned int w3) {
    union { bf16x8 v; unsigned int u[4]; } r;
    r.u[0] = w0; r.u[1] = w1; r.u[2] = w2; r.u[3] = w3;
    return r.v;
}

// ---------------- kernel 1: QKV projection as MFMA GEMM ----------------
__global__ __launch_bounds__(256) void qkv_kernel(
    const float* __restrict__ x,
    const float* __restrict__ Wq, const float* __restrict__ bq,
    const float* __restrict__ Wk, const float* __restrict__ bk,
    const float* __restrict__ Wv, const float* __restrict__ bv,
    unsigned short* __restrict__ qout, unsigned short* __restrict__ kout,
    unsigned short* __restrict__ vout)
{
    const int t = threadIdx.x;
    const int lane = t & 63, wv = t >> 6;
    const int a = lane & 15, g = lane >> 4;

    bf16x8 wf[5][2];
    #pragma unroll
    for (int T = 0; T < 5; ++T) {
        const float* wrow;
        float scale = 1.f;
        if (T == 0) {
            if (a < 8) { wrow = Wq + a*CC; scale = LOG2E; }
            else       { wrow = Wk + (a-8)*CC; }
        } else {
            wrow = Wv + ((T-1)*16 + a)*CC;
        }
        #pragma unroll
        for (int h = 0; h < 2; ++h) {
            float4 w0 = *(const float4*)(wrow + h*32 + g*8);
            float4 w1 = *(const float4*)(wrow + h*32 + g*8 + 4);
            wf[T][h] = pack8(w0.x*scale, w0.y*scale, w0.z*scale, w0.w*scale,
                             w1.x*scale, w1.y*scale, w1.z*scale, w1.w*scale);
        }
    }
    f32x4 bias[5];
    {
        const int r = g*4;
        #pragma unroll
        for (int u = 0; u < 4; ++u) {
            int rr = r + u;
            bias[0][u] = (rr < 8) ? bq[rr]*LOG2E : bk[rr-8];
        }
        #pragma unroll
        for (int T = 1; T < 5; ++T)
            #pragma unroll
            for (int u = 0; u < 4; ++u)
                bias[T][u] = bv[(T-1)*16 + r + u];
    }

    const int wave_id = blockIdx.x*4 + wv;
    #pragma unroll 1
    for (int it = 0; it < 2; ++it) {
        const int chunk = wave_id + it*4096;
        const int b = chunk >> 11;
        const int n0 = (chunk & 2047) * 16;
        const int n = n0 + a;
        const float* xcol = x + (size_t)b*CC*NN + n;

        float xv0[8], xv1[8];
        #pragma unroll
        for (int u = 0; u < 8; ++u) xv0[u] = xcol[(size_t)(g*8 + u)*NN];
        #pragma unroll
        for (int u = 0; u < 8; ++u) xv1[u] = xcol[(size_t)(32 + g*8 + u)*NN];
        bf16x8 xb0 = pack8(xv0[0],xv0[1],xv0[2],xv0[3],xv0[4],xv0[5],xv0[6],xv0[7]);
        bf16x8 xb1 = pack8(xv1[0],xv1[1],xv1[2],xv1[3],xv1[4],xv1[5],xv1[6],xv1[7]);

        f32x4 acc[5];
        #pragma unroll
        for (int T = 0; T < 5; ++T) {
            acc[T] = __builtin_amdgcn_mfma_f32_16x16x32_bf16(wf[T][0], xb0, bias[T], 0, 0, 0);
            acc[T] = __builtin_amdgcn_mfma_f32_16x16x32_bf16(wf[T][1], xb1, acc[T], 0, 0, 0);
        }

        {
            unsigned int lo = pack_bf16(acc[0][0], acc[0][1]);
            unsigned int hi = pack_bf16(acc[0][2], acc[0][3]);
            unsigned short* base = ((g < 2) ? qout : kout) + ((size_t)b*NN + n)*8 + (g & 1)*4;
            *(int2*)base = make_int2((int)lo, (int)hi);
        }
        #pragma unroll
        for (int T = 1; T < 5; ++T) {
            #pragma unroll
            for (int u = 0; u < 4; ++u) {
                const int e = (T-1)*16 + g*4 + u;
                vout[((size_t)b*CC + e)*NN + n] = to_bf16(acc[T][u]);
            }
        }
    }
}

// ---------------- kernel 2: windowed attention, 32x32x16 MFMA ----------------
// Wave = 32 i x 64 c (i-split: exp/(i,j) unchanged, acc halved, chain halved).
// Block = 4 waves = 128 i quarter of a window; grid = B*NWIN*4 = 2032 = 8x254.
// E is software-pipelined ONE jt AHEAD: Enext = mfma(sK[jt+1], qf) issues at the
// top of the body (reads only the immutable staged K window), while exp/pack/PV
// consume Ecur -> the E-MFMA latency leaves the per-jt critical path.
// K window staged once (8KB); V tile (32j x 64c) double-buffered per jt.
__global__ __launch_bounds__(256) void attn_kernel(
    const unsigned short* __restrict__ qg, const unsigned short* __restrict__ kg,
    const unsigned short* __restrict__ vg,
    unsigned short* __restrict__ accE, unsigned short* __restrict__ accO)
{
    __shared__ unsigned short sK[WW][8];        // 8 KB, [j][d]
    __shared__ unsigned short sV[2][64][36];    // 2 x 4.5 KB, [c][j-local], 72B rows
    __shared__ float sInv[4][32];
    const int t = threadIdx.x;
    const int lane = t & 63, wv = t >> 6;
    const int l31 = lane & 31, hi = lane >> 5;
    int bid = (blockIdx.x & 7)*254 + (blockIdx.x >> 3);   // XCD bijective swizzle (8x254)
    const int q2 = bid & 3; bid >>= 2;                    // window quarter (128 i)
    const int w = bid % NWIN, b = bid / NWIN;
    const int nwin = STR * w;
    const int i0 = q2*128 + wv*32;

    const unsigned short* qbase = qg + ((size_t)b*NN + nwin + i0)*8;
    const unsigned short* kbase = kg + ((size_t)b*NN + nwin)*8;
    const unsigned short* vsrc  = vg + ((size_t)b*CC + (t >> 2))*NN + nwin + (t & 3)*8;

    // ---- stage K window (coalesced, 2 x 16B per thread) ----
    #pragma unroll
    for (int m = 0; m < 2; ++m) {
        const int row = m*256 + t;
        *(int4*)&sK[row][0] = *(const int4*)(kbase + (size_t)row*8);
    }
    // ---- stage V tile jt=0 ----
    {
        int4 r = *(const int4*)vsrc;
        unsigned short* dst = &sV[0][t >> 2][(t & 3)*8];
        *(int2*)dst = *(int2*)&r;
        *(int2*)(dst + 4) = *((int2*)&r + 1);
    }

    const bf16x8 zf = {};
    // Q B-frag: col i = l31, k = d = 8*hi+e; hi half zeroed (d-pad annihilates)
    bf16x8 qf;
    {
        bf16x8 raw = *(const bf16x8*)(qbase + (size_t)l31*8);
        qf = hi ? zf : raw;
    }

    f32x16 acc[2] = {};    // [ct]
    float2 rsum2 = make_float2(0.f, 0.f);

    __syncthreads();

    // prologue: E for jt=0
    f32x16 Ecur;
    {
        const f32x16 z16 = {};
        bf16x8 kc = *(const bf16x8*)&sK[l31][0];
        Ecur = __builtin_amdgcn_mfma_f32_32x32x16_bf16(kc, qf, z16, 0, 0, 0);
    }

    for (int jt = 0; jt < 16; ++jt) {
        const int j0 = jt*32;
        const int cur = jt & 1;
        // (1) issue next tile's global V loads (T14: latency hides under compute)
        int4 stg;
        if (jt < 15) stg = *(const int4*)(vsrc + j0 + 32);
        // (2) issue next tile's E (depends only on immutable sK + qf)
        f32x16 Enext;
        if (jt < 15) {
            const f32x16 z16 = {};
            bf16x8 kn = *(const bf16x8*)&sK[j0 + 32 + l31][0];
            Enext = __builtin_amdgcn_mfma_f32_32x32x16_bf16(kn, qf, z16, 0, 0, 0);
        }
        // (3) V frags from LDS: c = ct*32+l31, j-local = sl*16 + hi*8
        bf16x8 vf[2][2];
        #pragma unroll
        for (int ct = 0; ct < 2; ++ct)
            #pragma unroll
            for (int sl = 0; sl < 2; ++sl) {
                const unsigned short* p = &sV[cur][ct*32 + l31][sl*16 + hi*8];
                union { bf16x8 v; int2 d[2]; } u;
                u.d[0] = *(const int2*)p;
                u.d[1] = *(const int2*)(p + 4);
                vf[ct][sl] = u.v;
            }
        // (4) softmax numerators from Ecur
        float p[16];
        #pragma unroll
        for (int r = 0; r < 16; ++r) p[r] = fast_exp2(Ecur[r]);
        float2 s0 = make_float2(p[0],  p[1])  + make_float2(p[2],  p[3]);
        float2 s1 = make_float2(p[4],  p[5])  + make_float2(p[6],  p[7]);
        float2 s2 = make_float2(p[8],  p[9])  + make_float2(p[10], p[11]);
        float2 s3 = make_float2(p[12], p[13]) + make_float2(p[14], p[15]);
        rsum2 += (s0 + s1) + (s2 + s3);
        unsigned int wd[8];
        #pragma unroll
        for (int tw = 0; tw < 8; ++tw) wd[tw] = pack_bf16(p[2*tw], p[2*tw+1]);
        unsigned int F0 = wd[0], F2 = wd[2]; plswap(F0, F2);
        unsigned int F1 = wd[1], F3 = wd[3]; plswap(F1, F3);
        unsigned int G0 = wd[4], G2 = wd[6]; plswap(G0, G2);
        unsigned int G1 = wd[5], G3 = wd[7]; plswap(G1, G3);
        bf16x8 pa0 = words4(F0, F1, F2, F3);   // k-slab j0+0..15
        bf16x8 pa1 = words4(G0, G1, G2, G3);   // k-slab j0+16..31
        // (5) PV
        #pragma unroll
        for (int ct = 0; ct < 2; ++ct) {
            acc[ct] = __builtin_amdgcn_mfma_f32_32x32x16_bf16(pa0, vf[ct][0], acc[ct], 0, 0, 0);
            acc[ct] = __builtin_amdgcn_mfma_f32_32x32x16_bf16(pa1, vf[ct][1], acc[ct], 0, 0, 0);
        }
        // (6) write next V tile into the other buffer, sync, rotate E
        if (jt < 15) {
            unsigned short* dst = &sV[cur ^ 1][t >> 2][(t & 3)*8];
            *(int2*)dst = *(int2*)&stg;
            *(int2*)(dst + 4) = *((int2*)&stg + 1);
        }
        __syncthreads();
        Ecur = Enext;
    }

    // ---- normalization: combine hi/lo j-halves, broadcast 1/r via LDS ----
    float r = rsum2.x + rsum2.y;
    r += __shfl_xor(r, 32);
    if (lane < 32) sInv[wv][lane] = 1.f / r;
    f32x4 invv[4];
    #pragma unroll
    for (int g = 0; g < 4; ++g)
        invv[g] = *(const f32x4*)&sInv[wv][8*g + 4*hi];

    unsigned short* ob = ((w & 1) ? accO : accE) + (size_t)b*CC*NN + nwin + i0;
    #pragma unroll
    for (int ct = 0; ct < 2; ++ct) {
        unsigned short* cbase = ob + (size_t)(ct*32 + l31)*NN;
        #pragma unroll
        for (int g = 0; g < 4; ++g) {
            float a0 = acc[ct][4*g+0] * invv[g][0];
            float a1 = acc[ct][4*g+1] * invv[g][1];
            float a2 = acc[ct][4*g+2] * invv[g][2];
            float a3 = acc[ct][4*g+3] * invv[g][3];
            int2 pw = make_int2((int)pack_bf16(a0, a1), (int)pack_bf16(a2, a3));
            *(int2*)(cbase + 8*g + 4*hi) = pw;
        }
    }
}

// ---------------- kernel 3: combine + 2:1 maxpool ----------------
__global__ __launch_bounds__(256) void final_kernel(
    const float* __restrict__ x,
    const unsigned short* __restrict__ accE, const unsigned short* __restrict__ accO,
    const float* __restrict__ gamma, float* __restrict__ out)
{
    const size_t tid = (size_t)blockIdx.x*256 + threadIdx.x;  // B*C*N/8 threads
    const size_t base = tid*8;
    const int n = (int)(base & (NN-1));
    const float g = gamma[0];

    float xv[8];
    *(float4*)&xv[0] = *(const float4*)&x[base];
    *(float4*)&xv[4] = *(const float4*)&x[base+4];
    int4 aeq = *(const int4*)&accE[base];
    const unsigned int* ae = (const unsigned int*)&aeq;

    float s[8];
    if (n >= STR && n < NN - STR) {
        int4 aoq = *(const int4*)&accO[base];
        const unsigned int* ao = (const unsigned int*)&aoq;
        #pragma unroll
        for (int u = 0; u < 4; ++u) {
            float e0 = bf2f((unsigned short)(ae[u] & 0xffff));
            float e1 = bf2f((unsigned short)(ae[u] >> 16));
            float o0 = bf2f((unsigned short)(ao[u] & 0xffff));
            float o1 = bf2f((unsigned short)(ao[u] >> 16));
            s[2*u]   = fmaf(g, (e0 + o0)*0.5f, xv[2*u]);
            s[2*u+1] = fmaf(g, (e1 + o1)*0.5f, xv[2*u+1]);
        }
    } else {
        #pragma unroll
        for (int u = 0; u < 4; ++u) {
            float e0 = bf2f((unsigned short)(ae[u] & 0xffff));
            float e1 = bf2f((unsigned short)(ae[u] >> 16));
            s[2*u]   = fmaf(g, e0, xv[2*u]);
            s[2*u+1] = fmaf(g, e1, xv[2*u+1]);
        }
    }
    float4 o = make_float4(fmaxf(s[0], s[1]), fmaxf(s[2], s[3]),
                           fmaxf(s[4], s[5]), fmaxf(s[6], s[7]));
    *(float4*)&out[tid*4] = o;
}

extern "C" void kernel_launch(void* const* d_in, const int* in_sizes, int n_in,
                              void* d_out, int out_size, void* d_ws, size_t ws_size,
                              hipStream_t stream)
{
    const float* x    = (const float*)d_in[0];
    const float* Wq   = (const float*)d_in[1];
    const float* bq   = (const float*)d_in[2];
    const float* Wk   = (const float*)d_in[3];
    const float* bk   = (const float*)d_in[4];
    const float* Wv   = (const float*)d_in[5];
    const float* bv   = (const float*)d_in[6];
    const float* gamma= (const float*)d_in[7];

    unsigned short* q    = (unsigned short*)d_ws;
    unsigned short* k    = q + (size_t)BB*NN*DD;
    unsigned short* v    = k + (size_t)BB*NN*DD;
    unsigned short* accE = v + (size_t)BB*CC*NN;
    unsigned short* accO = accE + (size_t)BB*CC*NN;
    float* out = (float*)d_out;

    qkv_kernel<<<1024, 256, 0, stream>>>(x, Wq, bq, Wk, bk, Wv, bv, q, k, v);
    attn_kernel<<<BB*NWIN*4, 256, 0, stream>>>(q, k, v, accE, accO);
    final_kernel<<<BB*CC*NN/8/256, 256, 0, stream>>>(x, accE, accO, gamma, out);
}